// Round 10
// baseline (87.757 us; speedup 1.0000x reference)
//
#include <hip/hip_runtime.h>
#include <math.h>

#define NB   4
#define SL   1024
#define NTOK (NB*SL)      // 4096
#define DM   64
#define DI   128
#define DSt  128
#define SEGLEN 16
#define NSEG (SL/SEGLEN)  // 64

// ---- workspace layout (float offsets) ----
#define OFF_GATE   0
#define OFF_DELTA  (OFF_GATE  + NTOK*DI)        // [tok][32 ic][12] = d,d2,d3 interleaved
#define OFF_BM     (OFF_DELTA + NTOK*384)
#define OFF_CM     (OFF_BM    + NTOK*DSt)
#define OFF_XPOOL  (OFF_CM    + NTOK*DSt)
#define OFF_ABAR   (OFF_XPOOL + NTOK)
#define OFF_HEND   (OFF_ABAR  + NTOK*DSt)       // 256 segs x 128
#define OFF_P      (OFF_HEND  + NB*NSEG*DSt)
#define OFF_Y      (OFF_P     + NB*NSEG*DSt)
#define OFF_W4     (OFF_Y     + NTOK)           // 2048 float4
#define OFF_AT1    (OFF_W4    + DM*DI)          // [s][i] = A[i][s]/128
#define OFF_AT2    (OFF_AT1   + DI*DSt)         // A^2/(2*128)
#define OFF_AT3    (OFF_AT2   + DI*DSt)         // A^3/(6*128)

#define PROJ_TOK 32
#define PROJ_TG  (NTOK/PROJ_TOK)   // 128

static __device__ __forceinline__ float wave64_sum(float v) {
#pragma unroll
    for (int m = 32; m >= 1; m >>= 1) v += __shfl_xor(v, m, 64);
    return v;
}

static __device__ __forceinline__ float softplus_f(float x) {
    return fmaxf(x, 0.f) + __logf(1.f + __expf(-fabsf(x)));
}

static __device__ __forceinline__ void pin4(float4& v) {
    asm volatile("" : "+v"(v.x), "+v"(v.y), "+v"(v.z), "+v"(v.w));
}

// ---- K1: projections + prep. grid = 512 main + 4 tail blocks.
// Main: 2 weight rows/lane pinned in VGPRs; x read at wave-uniform addresses
// (scalar-load path) -> inner loop pure v_fma, zero LDS traffic.
// cat1 stores d, d^2, d^3 interleaved for K2's scalar reads.
__global__ __launch_bounds__(256, 2) void k_proj(
    const float* __restrict__ x, const float* __restrict__ W_in,
    const float* __restrict__ W_delta, const float* __restrict__ b_delta,
    const float* __restrict__ W_B, const float* __restrict__ b_B,
    const float* __restrict__ W_C, const float* __restrict__ b_C,
    const float* __restrict__ A, const float* __restrict__ W_out,
    float* __restrict__ ws)
{
    __shared__ float4 Wl[DI*16];
    const int tid = threadIdx.x;

    if (blockIdx.x >= 512) {                 // tail blocks: prep
        const int e = blockIdx.x - 512;
        if (e < 3) {                         // A-power transposes
            float* At = ws + (e == 0 ? OFF_AT1 : (e == 1 ? OFF_AT2 : OFF_AT3));
            const float sc = (e == 0) ? (1.f/128.f) : (e == 1 ? 1.f/256.f : 1.f/768.f);
            for (int f = tid; f < DI*DSt; f += 256) {
                const int i = f >> 7, s = f & 127;
                const float a = A[f];                       // coalesced read
                const float v = (e == 0) ? a*sc : (e == 1 ? a*a*sc : a*a*a*sc);
                At[s*DI + i] = v;                           // transpose scatter
            }
        } else {                             // W_out repack: W4[q*64+d]
            const float4* Wg = (const float4*)W_out;
            float4* W4 = (float4*)(ws + OFF_W4);
#pragma unroll
            for (int j = 0; j < 8; ++j) {
                const int f = tid + j*256;
                const int d = f >> 5, q = f & 31;
                W4[q*64 + d] = Wg[f];
            }
        }
        return;
    }

    const int l   = tid & 63;
    const int w   = tid >> 6;
    const int cat = blockIdx.x >> 7;
    const int tg  = blockIdx.x & 127;
    const int tok0 = tg * PROJ_TOK;

    const float* Wbase; const float* bias; float* dst;
    if      (cat == 0) { Wbase = W_in + DI*DM; bias = nullptr; dst = ws + OFF_GATE;  }
    else if (cat == 1) { Wbase = W_delta;      bias = b_delta; dst = ws + OFF_DELTA; }
    else if (cat == 2) { Wbase = W_B;          bias = b_B;     dst = ws + OFF_BM;    }
    else               { Wbase = W_C;          bias = b_C;     dst = ws + OFF_CM;    }

    {   // stage weight panel coalesced -> swizzled LDS
        const float4* Wg = (const float4*)Wbase;
#pragma unroll
        for (int j = 0; j < 8; ++j) {
            const int f = tid + j*256;
            const int row = f >> 4, k = f & 15;
            Wl[row*16 + (k ^ (row & 15))] = Wg[f];
        }
    }
    __syncthreads();

    float4 w0[16], w1[16];
#pragma unroll
    for (int k = 0; k < 16; ++k) {
        w0[k] = Wl[l*16      + (k ^ (l & 15))];
        w1[k] = Wl[(l+64)*16 + (k ^ (l & 15))];
    }
#pragma unroll
    for (int k = 0; k < 16; ++k) { pin4(w0[k]); pin4(w1[k]); }

    float bias0 = 0.f, bias1 = 0.f;
    if (bias) { bias0 = bias[l]; bias1 = bias[l+64]; }

#pragma unroll 2
    for (int it = 0; it < 8; ++it) {
        const int tlu = __builtin_amdgcn_readfirstlane(it*4 + w);  // uniform
        const float* xt = x + (tok0 + tlu)*DM;
        float a0=0.f,a1=0.f,a2=0.f,a3=0.f, c0=0.f,c1=0.f,c2=0.f,c3=0.f;
#pragma unroll
        for (int k = 0; k < 16; ++k) {
            const float4 xv = *(const float4*)(xt + 4*k);   // uniform -> s_load
            a0 = fmaf(w0[k].x, xv.x, a0);
            a1 = fmaf(w0[k].y, xv.y, a1);
            a2 = fmaf(w0[k].z, xv.z, a2);
            a3 = fmaf(w0[k].w, xv.w, a3);
            c0 = fmaf(w1[k].x, xv.x, c0);
            c1 = fmaf(w1[k].y, xv.y, c1);
            c2 = fmaf(w1[k].z, xv.z, c2);
            c3 = fmaf(w1[k].w, xv.w, c3);
        }
        float ra = (a0+a1) + (a2+a3) + bias0;
        float rb = (c0+c1) + (c2+c3) + bias1;
        const int tok = tok0 + tlu;
        if (cat == 1) {
            const float d0 = softplus_f(ra), d1 = softplus_f(rb);
            const float d0q = d0*d0, d1q = d1*d1;
            float* p0 = dst + tok*384 + (l>>2)*12 + (l&3);
            float* p1 = dst + tok*384 + ((l+64)>>2)*12 + (l&3);
            p0[0] = d0;  p0[4] = d0q;  p0[8] = d0q*d0;
            p1[0] = d1;  p1[4] = d1q;  p1[8] = d1q*d1;
        } else {
            dst[tok*128 + l]      = ra;
            dst[tok*128 + 64 + l] = rb;
        }
    }

    if (cat == 0) {   // x_pool = x . w_pool
        float wp = 0.f;
#pragma unroll 8
        for (int i = 0; i < DI; ++i) wp += W_in[i*DM + l];
        wp *= (1.0f/DI);
#pragma unroll
        for (int it = 0; it < 8; ++it) {
            const int tl = it*4 + w;
            float v = x[(tok0 + tl)*DM + l] * wp;
            v = wave64_sum(v);
            if (l == 0) ws[OFF_XPOOL + tok0 + tl] = v;
        }
    }
}

// ---- K2: Abar (Taylor-3 matvec) + scan1. grid = 128 tgroups x 2 s-halves.
// Block: 32 tokens x 64 states. A-power panels in swizzled LDS (96 KB,
// 2-way reads = free); delta powers via wave-uniform scalar loads (SGPR
// FMA operands). Then 16-step scan1 for 2 segments from LDS Abar.
__global__ __launch_bounds__(256) void k_abar_scan1(float* __restrict__ ws)
{
    __shared__ float4 AkL[3][64][32];   // 96 KB, [term][s][ic ^ (s&31)]
    __shared__ float  abL[32][64];      // 8 KB
    const int tid = threadIdx.x;
    const int tg  = blockIdx.x >> 1;
    const int sh  = blockIdx.x & 1;     // s-half
    const int tok0 = tg * 32;

    {   // stage A-power panels (rows sh*64..+64), coalesced reads
#pragma unroll
        for (int k = 0; k < 3; ++k) {
            const float* At = ws + (k == 0 ? OFF_AT1 : (k == 1 ? OFF_AT2 : OFF_AT3));
            const float4* Ag = (const float4*)(At + sh*64*DI);
#pragma unroll
            for (int j = 0; j < 8; ++j) {
                const int f = tid + j*256;      // f4 index over [64][32]
                const int sl = f >> 5, ic = f & 31;
                AkL[k][sl][ic ^ (sl & 31)] = Ag[f];
            }
        }
    }
    __syncthreads();

    {   // Abar compute: wave w handles tokens tok0 + w*8 .. +8
        const int lane = tid & 63;
        const int wu   = __builtin_amdgcn_readfirstlane(tid >> 6);
        const float* dbase = ws + OFF_DELTA + (tok0 + wu*8)*384;
        float acc[8];
#pragma unroll
        for (int j = 0; j < 8; ++j) acc[j] = 1.0f;

        for (int ic = 0; ic < 32; ++ic) {
            const int sw = ic ^ (lane & 31);
            const float4 a1 = AkL[0][lane][sw];
            const float4 a2 = AkL[1][lane][sw];
            const float4 a3 = AkL[2][lane][sw];
#pragma unroll
            for (int j = 0; j < 8; ++j) {
                const float* dp = dbase + j*384 + ic*12;   // uniform -> s_load
                float t = acc[j];
                t = fmaf(dp[0], a1.x, t); t = fmaf(dp[1], a1.y, t);
                t = fmaf(dp[2], a1.z, t); t = fmaf(dp[3], a1.w, t);
                t = fmaf(dp[4], a2.x, t); t = fmaf(dp[5], a2.y, t);
                t = fmaf(dp[6], a2.z, t); t = fmaf(dp[7], a2.w, t);
                t = fmaf(dp[8], a3.x, t); t = fmaf(dp[9], a3.y, t);
                t = fmaf(dp[10], a3.z, t); t = fmaf(dp[11], a3.w, t);
                acc[j] = t;
            }
        }
        float* Abar = ws + OFF_ABAR;
#pragma unroll
        for (int j = 0; j < 8; ++j) {
            const int tl = wu*8 + j;
            abL[tl][lane] = acc[j];
            Abar[(tok0 + tl)*DSt + sh*64 + lane] = acc[j];   // coalesced
        }
    }
    __syncthreads();

    if (tid < 128) {   // scan1: 2 segments x 64 states
        const int sg = tid >> 6, sl = tid & 63;
        const int sglob = sh*64 + sl;
        const int seg_lin = tg*2 + sg;          // global segment index
        const float* Bm    = ws + OFF_BM;
        const float* xpool = ws + OFF_XPOOL;
        float bx[SEGLEN];
#pragma unroll
        for (int t = 0; t < SEGLEN; ++t) {
            const int tok = tok0 + sg*16 + t;
            bx[t] = Bm[tok*DSt + sglob] * xpool[tok];
        }
        float h = 0.f, pr = 1.f;
#pragma unroll
        for (int t = 0; t < SEGLEN; ++t) {
            const float a = abL[sg*16 + t][sl];
            h = fmaf(a, h, bx[t]);
            pr *= a;
        }
        ws[OFF_HEND + seg_lin*DSt + sglob] = h;
        ws[OFF_P    + seg_lin*DSt + sglob] = pr;
    }
}

// ---- K3: y. grid = 256 blocks x 128 threads ----
__global__ __launch_bounds__(128) void k_y(float* __restrict__ ws)
{
    __shared__ float prod[SEGLEN][132];
    const int s   = threadIdx.x;
    const int b   = blockIdx.x >> 6;
    const int seg = blockIdx.x & 63;
    const float* Abar  = ws + OFF_ABAR;
    const float* Bm    = ws + OFF_BM;
    const float* Cm    = ws + OFF_CM;
    const float* xpool = ws + OFF_XPOOL;
    const float* hend  = ws + OFF_HEND;
    const float* P     = ws + OFF_P;
    const int t0 = b*SL + seg*SEGLEN;

    float aA[SEGLEN], aB[SEGLEN], aC[SEGLEN];
#pragma unroll
    for (int t = 0; t < SEGLEN; ++t) {
        aA[t] = Abar[(t0 + t)*DSt + s];
        aB[t] = Bm[(t0 + t)*DSt + s] * xpool[t0 + t];
        aC[t] = Cm[(t0 + t)*DSt + s];
    }
    float h = 0.f;
#pragma unroll 8
    for (int j = 0; j < seg; ++j) {
        const int idx = (b*NSEG + j)*DSt + s;
        h = fmaf(P[idx], h, hend[idx]);
    }
#pragma unroll
    for (int t = 0; t < SEGLEN; ++t) {
        h = fmaf(aA[t], h, aB[t]);
        prod[t][s] = aC[t] * h;
    }
    __syncthreads();

    const int t = s >> 3, r = s & 7;
    float4 acc4 = {0.f,0.f,0.f,0.f};
#pragma unroll
    for (int k4 = 0; k4 < 4; ++k4) {
        const float4 v = *(const float4*)(&prod[t][r*16 + 4*k4]);
        acc4.x += v.x; acc4.y += v.y; acc4.z += v.z; acc4.w += v.w;
    }
    float acc = (acc4.x + acc4.y) + (acc4.z + acc4.w);
#pragma unroll
    for (int m = 1; m <= 4; m <<= 1) acc += __shfl_xor(acc, m, 64);
    if (r == 0) ws[OFF_Y + b*SL + seg*SEGLEN + t] = acc;
}

// ---- K4: output. grid = 1024 x 256; W_out from global repack ----
__global__ __launch_bounds__(256) void k_out(
    const float* __restrict__ x, const float* __restrict__ ln_w,
    const float* __restrict__ ln_b, const float* __restrict__ ws,
    float* __restrict__ out)
{
    __shared__ float vbuf[4][DI];
    const int tid = threadIdx.x;
    const int d   = tid & 63;
    const int wv  = tid >> 6;
    const int tok = blockIdx.x*4 + wv;

    const float* gate = ws + OFF_GATE;
    const float* y    = ws + OFF_Y;
    const float4* W4  = (const float4*)(ws + OFF_W4);

    const float yt = y[tok];
    const float g0 = gate[tok*DI + d];
    const float g1 = gate[tok*DI + 64 + d];
    vbuf[wv][d]      = yt * (g0 / (1.f + __expf(-g0)));
    vbuf[wv][64 + d] = yt * (g1 / (1.f + __expf(-g1)));
    __syncthreads();

    float ac0 = 0.f, ac1 = 0.f, ac2 = 0.f, ac3 = 0.f;
#pragma unroll 8
    for (int q = 0; q < 32; ++q) {
        const float4 wv4 = W4[q*64 + d];
        const float4 vv  = *(const float4*)(&vbuf[wv][q*4]);
        ac0 = fmaf(wv4.x, vv.x, ac0);
        ac1 = fmaf(wv4.y, vv.y, ac1);
        ac2 = fmaf(wv4.z, vv.z, ac2);
        ac3 = fmaf(wv4.w, vv.w, ac3);
    }
    const float z  = (ac0+ac1) + (ac2+ac3) + x[tok*DM + d];
    const float s1 = wave64_sum(z);
    const float s2 = wave64_sum(z*z);
    const float mu  = s1 * (1.f/64.f);
    const float var = s2 * (1.f/64.f) - mu*mu;
    out[tok*DM + d] = (z - mu) * rsqrtf(var + 1e-5f) * ln_w[d] + ln_b[d];
}

extern "C" void kernel_launch(void* const* d_in, const int* in_sizes, int n_in,
                              void* d_out, int out_size, void* d_ws, size_t ws_size,
                              hipStream_t stream) {
    const float* x       = (const float*)d_in[0];
    const float* W_in    = (const float*)d_in[1];
    const float* W_delta = (const float*)d_in[2];
    const float* b_delta = (const float*)d_in[3];
    const float* W_B     = (const float*)d_in[4];
    const float* b_B     = (const float*)d_in[5];
    const float* W_C     = (const float*)d_in[6];
    const float* b_C     = (const float*)d_in[7];
    const float* A       = (const float*)d_in[8];
    const float* W_out   = (const float*)d_in[9];
    const float* ln_w    = (const float*)d_in[10];
    const float* ln_b    = (const float*)d_in[11];
    float* out = (float*)d_out;
    float* ws  = (float*)d_ws;

    hipLaunchKernelGGL(k_proj, dim3(516), dim3(256), 0, stream,
                       x, W_in, W_delta, b_delta, W_B, b_B, W_C, b_C, A, W_out, ws);
    hipLaunchKernelGGL(k_abar_scan1, dim3(256),  dim3(256), 0, stream, ws);
    hipLaunchKernelGGL(k_y,          dim3(256),  dim3(128), 0, stream, ws);
    hipLaunchKernelGGL(k_out,        dim3(1024), dim3(256), 0, stream,
                       x, ln_w, ln_b, ws, out);
}

// Round 11
// 50.060 us; speedup vs baseline: 1.7530x; 1.7530x over previous
//
#include <hip/hip_runtime.h>
#include <math.h>

#define NB   4
#define SL   1024
#define NTOK (NB*SL)      // 4096
#define DM   64
#define DI   128
#define DSt  128
#define SEGLEN 8
#define NSEG (SL/SEGLEN)  // 128
#define NSEG_ALL (NB*NSEG) // 512

// ---- workspace layout (float offsets) ----
#define OFF_GATE   0
#define OFF_DELTA  (OFF_GATE  + NTOK*DI)
#define OFF_BM     (OFF_DELTA + NTOK*DI)
#define OFF_CM     (OFF_BM    + NTOK*DSt)
#define OFF_XPOOL  (OFF_CM    + NTOK*DSt)
#define OFF_ABAR   (OFF_XPOOL + NTOK)
#define OFF_HEND   (OFF_ABAR  + NTOK*DSt)
#define OFF_P      (OFF_HEND  + NSEG_ALL*DSt)
#define OFF_Y      (OFF_P     + NSEG_ALL*DSt)
#define OFF_W4     (OFF_Y     + NTOK)        // 2048 float4

#define PROJ_TOK 16
#define PROJ_TG  (NTOK/PROJ_TOK)   // 256 token groups

static __device__ __forceinline__ float wave64_sum(float v) {
#pragma unroll
    for (int m = 32; m >= 1; m >>= 1) v += __shfl_xor(v, m, 64);
    return v;
}

static __device__ __forceinline__ float fast_exp2(float x) {
    float r;
    asm("v_exp_f32 %0, %1" : "=v"(r) : "v"(x));
    return r;
}

static __device__ __forceinline__ float softplus_f(float x) {
    return fmaxf(x, 0.f) + __logf(1.f + __expf(-fabsf(x)));
}

static __device__ __forceinline__ void pin4(float4& v) {
    asm volatile("" : "+v"(v.x), "+v"(v.y), "+v"(v.z), "+v"(v.w));
}

// ---- K1: projections. grid = 4 cats x 256 token-groups (+1 repack block).
// 16 tokens/block -> 1024 blocks (2x R4) for latency hiding. Two weight
// rows/lane pinned in VGPRs; x tile in LDS read as broadcast; stores coalesced.
__global__ __launch_bounds__(256, 2) void k_proj(
    const float* __restrict__ x, const float* __restrict__ W_in,
    const float* __restrict__ W_delta, const float* __restrict__ b_delta,
    const float* __restrict__ W_B, const float* __restrict__ b_B,
    const float* __restrict__ W_C, const float* __restrict__ b_C,
    const float* __restrict__ W_out, float* __restrict__ ws)
{
    __shared__ float  xl[PROJ_TOK*DM];   // 4 KB
    __shared__ float4 Wl[DI*16];         // 32 KB
    const int tid = threadIdx.x;

    if (blockIdx.x == 4*PROJ_TG) {       // tail: W_out repack W4[q*64+d]
        const float4* Wg = (const float4*)W_out;
        float4* W4 = (float4*)(ws + OFF_W4);
#pragma unroll
        for (int j = 0; j < 8; ++j) {
            const int f = tid + j*256;
            const int d = f >> 5, q = f & 31;
            W4[q*64 + d] = Wg[f];
        }
        return;
    }

    const int l   = tid & 63;
    const int w   = tid >> 6;
    const int cat = blockIdx.x >> 8;     // 0 gate, 1 delta, 2 B, 3 C
    const int tg  = blockIdx.x & 255;
    const int tok0 = tg * PROJ_TOK;

    const float* Wbase; const float* bias; float* dst;
    if      (cat == 0) { Wbase = W_in + DI*DM; bias = nullptr; dst = ws + OFF_GATE;  }
    else if (cat == 1) { Wbase = W_delta;      bias = b_delta; dst = ws + OFF_DELTA; }
    else if (cat == 2) { Wbase = W_B;          bias = b_B;     dst = ws + OFF_BM;    }
    else               { Wbase = W_C;          bias = b_C;     dst = ws + OFF_CM;    }

    {   // stage x tile (256 f4) + weight panel (2048 f4), coalesced
        const float4* xg = (const float4*)(x + tok0*DM);
        ((float4*)xl)[tid] = xg[tid];
        const float4* Wg = (const float4*)Wbase;
#pragma unroll
        for (int j = 0; j < 8; ++j) {
            const int f = tid + j*256;
            const int row = f >> 4, k = f & 15;
            Wl[row*16 + (k ^ (row & 15))] = Wg[f];
        }
    }
    __syncthreads();

    float4 w0[16], w1[16];
#pragma unroll
    for (int k = 0; k < 16; ++k) {
        w0[k] = Wl[l*16      + (k ^ (l & 15))];
        w1[k] = Wl[(l+64)*16 + (k ^ (l & 15))];
    }
#pragma unroll
    for (int k = 0; k < 16; ++k) { pin4(w0[k]); pin4(w1[k]); }

    float bias0 = 0.f, bias1 = 0.f;
    if (bias) { bias0 = bias[l]; bias1 = bias[l+64]; }

#pragma unroll
    for (int it = 0; it < PROJ_TOK/4; ++it) {
        const int tl = it*4 + w;        // wave-uniform local token
        float a0=0.f,a1=0.f,a2=0.f,a3=0.f, c0=0.f,c1=0.f,c2=0.f,c3=0.f;
#pragma unroll
        for (int k = 0; k < 16; ++k) {
            const float4 xv = *(const float4*)(xl + tl*DM + 4*k);  // broadcast
            a0 = fmaf(w0[k].x, xv.x, a0);
            a1 = fmaf(w0[k].y, xv.y, a1);
            a2 = fmaf(w0[k].z, xv.z, a2);
            a3 = fmaf(w0[k].w, xv.w, a3);
            c0 = fmaf(w1[k].x, xv.x, c0);
            c1 = fmaf(w1[k].y, xv.y, c1);
            c2 = fmaf(w1[k].z, xv.z, c2);
            c3 = fmaf(w1[k].w, xv.w, c3);
        }
        float ra = (a0+a1) + (a2+a3) + bias0;
        float rb = (c0+c1) + (c2+c3) + bias1;
        if (cat == 1) { ra = softplus_f(ra); rb = softplus_f(rb); }
        const int tok = tok0 + tl;
        dst[tok*128 + l]      = ra;   // coalesced 256B
        dst[tok*128 + 64 + l] = rb;
    }

    if (cat == 0) {   // x_pool = x . w_pool (mean folded into weights)
        float wp = 0.f;
#pragma unroll 8
        for (int i = 0; i < DI; ++i) wp += W_in[i*DM + l];   // coalesced, L2-hot
        wp *= (1.0f/DI);
#pragma unroll
        for (int it = 0; it < PROJ_TOK/4; ++it) {
            const int tl = it*4 + w;
            float v = xl[tl*DM + l] * wp;
            v = wave64_sum(v);
            if (l == 0) ws[OFF_XPOOL + tok0 + tl] = v;
        }
    }
}

// ---- K2: exp-Abar + 8-step scan1. Block = 8 tokens x 64 states.
// grid = 512 tok-groups x 2 s-halves = 1024 blocks x 4 waves = 16 waves/CU.
// Wave = one i-group of 32 (areg[32]/lane, no remat); psum reduced via LDS. ----
__global__ __launch_bounds__(256) void k_abar_scan1(const float* __restrict__ A,
                                                    float* __restrict__ ws)
{
    __shared__ float psum[4][SEGLEN][64];   // 8 KB
    __shared__ float abL[SEGLEN][64];       // 2 KB
    const int tid  = threadIdx.x;
    const int lane = tid & 63;
    const int igrp = tid >> 6;              // 0..3
    const int g    = blockIdx.x >> 1;       // token-group = global segment
    const int sh   = blockIdx.x & 1;
    const int s    = sh*64 + lane;
    const int t0   = g * SEGLEN;            // global token base

    float areg[32];
#pragma unroll
    for (int i = 0; i < 32; ++i)
        areg[i] = A[(igrp*32 + i)*DSt + s] * 1.44269504f;   // coalesced

    const float* delta = ws + OFF_DELTA;
    float*       Abar  = ws + OFF_ABAR;

#pragma unroll
    for (int t = 0; t < SEGLEN; ++t) {
        const float* dv = delta + (t0 + t)*DI + igrp*32;
        float a0=0.f,a1=0.f,a2=0.f,a3=0.f;
#pragma unroll
        for (int q = 0; q < 8; ++q) {
            const float4 d4 = *(const float4*)(dv + 4*q);   // uniform bcast
            a0 += fast_exp2(d4.x * areg[4*q    ]);
            a1 += fast_exp2(d4.y * areg[4*q + 1]);
            a2 += fast_exp2(d4.z * areg[4*q + 2]);
            a3 += fast_exp2(d4.w * areg[4*q + 3]);
        }
        psum[igrp][t][lane] = (a0+a1) + (a2+a3);   // stride-1: conflict-free
    }
    __syncthreads();

#pragma unroll
    for (int it = tid; it < SEGLEN*64; it += 256) {   // reduce 4 i-groups
        const int t = it >> 6, l2 = it & 63;
        float v = (psum[0][t][l2] + psum[1][t][l2])
                + (psum[2][t][l2] + psum[3][t][l2]);
        v *= (1.0f/DI);
        abL[t][l2] = v;
        Abar[(t0 + t)*DSt + sh*64 + l2] = v;          // coalesced 256B
    }
    __syncthreads();

    if (tid < 64) {   // 8-step local scan for this s-half
        const float* Bm    = ws + OFF_BM;
        const float* xpool = ws + OFF_XPOOL;
        float bx[SEGLEN];
#pragma unroll
        for (int t = 0; t < SEGLEN; ++t)
            bx[t] = Bm[(t0 + t)*DSt + s] * xpool[t0 + t];
        float h = 0.f, pr = 1.f;
#pragma unroll
        for (int t = 0; t < SEGLEN; ++t) {
            const float a = abL[t][lane];
            h = fmaf(a, h, bx[t]);
            pr *= a;
        }
        ws[OFF_HEND + g*DSt + s] = h;
        ws[OFF_P    + g*DSt + s] = pr;
    }
}

// ---- K3: y. grid = 512 blocks (one 8-token segment) x 128 threads ----
__global__ __launch_bounds__(128) void k_y(float* __restrict__ ws)
{
    __shared__ float prod[SEGLEN][132];
    const int s   = threadIdx.x;
    const int b   = blockIdx.x >> 7;
    const int seg = blockIdx.x & 127;
    const float* Abar  = ws + OFF_ABAR;
    const float* Bm    = ws + OFF_BM;
    const float* Cm    = ws + OFF_CM;
    const float* xpool = ws + OFF_XPOOL;
    const float* hend  = ws + OFF_HEND;
    const float* P     = ws + OFF_P;
    const int t0 = b*SL + seg*SEGLEN;

    float aA[SEGLEN], aB[SEGLEN], aC[SEGLEN];
#pragma unroll
    for (int t = 0; t < SEGLEN; ++t) {
        aA[t] = Abar[(t0 + t)*DSt + s];
        aB[t] = Bm[(t0 + t)*DSt + s] * xpool[t0 + t];
        aC[t] = Cm[(t0 + t)*DSt + s];
    }
    float h = 0.f;
#pragma unroll 8
    for (int j = 0; j < seg; ++j) {       // block-uniform trip count
        const int idx = (b*NSEG + j)*DSt + s;
        h = fmaf(P[idx], h, hend[idx]);
    }
#pragma unroll
    for (int t = 0; t < SEGLEN; ++t) {
        h = fmaf(aA[t], h, aB[t]);
        prod[t][s] = aC[t] * h;
    }
    __syncthreads();

    const int t = s >> 4, r = s & 15;     // 8 tokens x 16 lanes
    float4 u0 = *(const float4*)(&prod[t][r*8]);
    float4 u1 = *(const float4*)(&prod[t][r*8 + 4]);
    float acc = ((u0.x+u0.y) + (u0.z+u0.w)) + ((u1.x+u1.y) + (u1.z+u1.w));
#pragma unroll
    for (int m = 1; m <= 8; m <<= 1) acc += __shfl_xor(acc, m, 64);
    if (r == 0) ws[OFF_Y + b*SL + seg*SEGLEN + t] = acc;
}

// ---- K4: output. grid = 1024 x 256 (wave/token, 16 waves/CU).
// W_out from global repack (coalesced, L2-hot, zero bank pressure). ----
__global__ __launch_bounds__(256) void k_out(
    const float* __restrict__ x, const float* __restrict__ ln_w,
    const float* __restrict__ ln_b, const float* __restrict__ ws,
    float* __restrict__ out)
{
    __shared__ float vbuf[4][DI];
    const int tid = threadIdx.x;
    const int d   = tid & 63;
    const int wv  = tid >> 6;
    const int tok = blockIdx.x*4 + wv;

    const float* gate = ws + OFF_GATE;
    const float* y    = ws + OFF_Y;
    const float4* W4  = (const float4*)(ws + OFF_W4);

    const float yt = y[tok];
    const float g0 = gate[tok*DI + d];
    const float g1 = gate[tok*DI + 64 + d];
    vbuf[wv][d]      = yt * (g0 / (1.f + __expf(-g0)));
    vbuf[wv][64 + d] = yt * (g1 / (1.f + __expf(-g1)));
    __syncthreads();

    float ac0 = 0.f, ac1 = 0.f, ac2 = 0.f, ac3 = 0.f;
#pragma unroll 8
    for (int q = 0; q < 32; ++q) {
        const float4 wv4 = W4[q*64 + d];                     // coalesced 1KB
        const float4 vv  = *(const float4*)(&vbuf[wv][q*4]); // broadcast
        ac0 = fmaf(wv4.x, vv.x, ac0);
        ac1 = fmaf(wv4.y, vv.y, ac1);
        ac2 = fmaf(wv4.z, vv.z, ac2);
        ac3 = fmaf(wv4.w, vv.w, ac3);
    }
    const float z  = (ac0+ac1) + (ac2+ac3) + x[tok*DM + d];
    const float s1 = wave64_sum(z);
    const float s2 = wave64_sum(z*z);
    const float mu  = s1 * (1.f/64.f);
    const float var = s2 * (1.f/64.f) - mu*mu;
    out[tok*DM + d] = (z - mu) * rsqrtf(var + 1e-5f) * ln_w[d] + ln_b[d];
}

extern "C" void kernel_launch(void* const* d_in, const int* in_sizes, int n_in,
                              void* d_out, int out_size, void* d_ws, size_t ws_size,
                              hipStream_t stream) {
    const float* x       = (const float*)d_in[0];
    const float* W_in    = (const float*)d_in[1];
    const float* W_delta = (const float*)d_in[2];
    const float* b_delta = (const float*)d_in[3];
    const float* W_B     = (const float*)d_in[4];
    const float* b_B     = (const float*)d_in[5];
    const float* W_C     = (const float*)d_in[6];
    const float* b_C     = (const float*)d_in[7];
    const float* A       = (const float*)d_in[8];
    const float* W_out   = (const float*)d_in[9];
    const float* ln_w    = (const float*)d_in[10];
    const float* ln_b    = (const float*)d_in[11];
    float* out = (float*)d_out;
    float* ws  = (float*)d_ws;

    hipLaunchKernelGGL(k_proj, dim3(4*PROJ_TG + 1), dim3(256), 0, stream,
                       x, W_in, W_delta, b_delta, W_B, b_B, W_C, b_C, W_out, ws);
    hipLaunchKernelGGL(k_abar_scan1, dim3(2*NSEG_ALL), dim3(256), 0, stream, A, ws);
    hipLaunchKernelGGL(k_y,          dim3(NSEG_ALL),   dim3(128), 0, stream, ws);
    hipLaunchKernelGGL(k_out,        dim3(NTOK/4),     dim3(256), 0, stream,
                       x, ln_w, ln_b, ws, out);
}